// Round 1
// baseline (459.832 us; speedup 1.0000x reference)
//
#include <hip/hip_runtime.h>

#define D 48

// ---------------- CSR build ----------------

__global__ void k_hist(const int* __restrict__ dst, int* __restrict__ deg, int E) {
    int e = blockIdx.x * 256 + threadIdx.x;
    if (e < E) atomicAdd(&deg[dst[e]], 1);
}

__global__ void k_bsums(const int* __restrict__ deg, int* __restrict__ bsums, int n) {
    __shared__ int sh[256];
    int t = threadIdx.x;
    int base = blockIdx.x * 1024;
    int s = 0;
#pragma unroll
    for (int k = 0; k < 4; k++) {
        int i = base + k * 256 + t;
        if (i < n) s += deg[i];
    }
    sh[t] = s;
    __syncthreads();
    for (int off = 128; off > 0; off >>= 1) {
        if (t < off) sh[t] += sh[t + off];
        __syncthreads();
    }
    if (t == 0) bsums[blockIdx.x] = sh[0];
}

__global__ void k_scan_small(int* __restrict__ b, int n) {
    if (threadIdx.x == 0 && blockIdx.x == 0) {
        int acc = 0;
        for (int i = 0; i < n; i++) { int t = b[i]; b[i] = acc; acc += t; }
    }
}

__global__ void k_scan_write(const int* __restrict__ deg, const int* __restrict__ bsums,
                             int* __restrict__ row_ptr, int* __restrict__ cursor,
                             int n, int E) {
    __shared__ int sh[256];
    int t = threadIdx.x;
    int base = blockIdx.x * 1024;
    int v[4];
    int tsum = 0;
#pragma unroll
    for (int k = 0; k < 4; k++) {
        int i = base + t * 4 + k;
        v[k] = (i < n) ? deg[i] : 0;
        tsum += v[k];
    }
    sh[t] = tsum;
    __syncthreads();
    // Hillis-Steele inclusive scan over 256 thread partials
    for (int off = 1; off < 256; off <<= 1) {
        int x = (t >= off) ? sh[t - off] : 0;
        __syncthreads();
        sh[t] += x;
        __syncthreads();
    }
    int run = bsums[blockIdx.x] + sh[t] - tsum;  // exclusive prefix for this thread
#pragma unroll
    for (int k = 0; k < 4; k++) {
        int i = base + t * 4 + k;
        if (i < n) { row_ptr[i] = run; cursor[i] = run; }
        run += v[k];
    }
    if (blockIdx.x == 0 && t == 0) row_ptr[n] = E;
}

__global__ void k_fill(const int* __restrict__ src, const int* __restrict__ dst,
                       int* __restrict__ cursor, int* __restrict__ esrc, int E) {
    int e = blockIdx.x * 256 + threadIdx.x;
    if (e < E) {
        int d = dst[e];
        int p = atomicAdd(&cursor[d], 1);
        esrc[p] = src[e];
    }
}

// ---------------- pull-mode aggregation ----------------
// 16 lanes per node; lane l owns features l, l+16, l+32.
// Each feature load is a 64B contiguous segment per 16-lane subgroup.

template <int RELU>
__global__ void k_pull(const float* __restrict__ hin, float* __restrict__ hout,
                       const int* __restrict__ row_ptr, const int* __restrict__ esrc,
                       int n) {
    int sub = threadIdx.x >> 4;
    int lane = threadIdx.x & 15;
    int node = blockIdx.x * 16 + sub;
    if (node >= n) return;
    int jb = row_ptr[node], je = row_ptr[node + 1];
    float a0 = 0.f, a1 = 0.f, a2 = 0.f;
    for (int j = jb; j < je; ++j) {
        int s = esrc[j];
        const float* r = hin + (size_t)s * D + lane;
        a0 += r[0];
        a1 += r[16];
        a2 += r[32];
    }
    if (RELU) {
        a0 = fmaxf(a0, 0.f);
        a1 = fmaxf(a1, 0.f);
        a2 = fmaxf(a2, 0.f);
    }
    float* o = hout + (size_t)node * D + lane;
    o[0] = a0;
    o[16] = a1;
    o[32] = a2;
}

extern "C" void kernel_launch(void* const* d_in, const int* in_sizes, int n_in,
                              void* d_out, int out_size, void* d_ws, size_t ws_size,
                              hipStream_t stream) {
    const float* feat = (const float*)d_in[0];
    const int* src = (const int*)d_in[1];
    const int* dst = (const int*)d_in[2];
    int N = in_sizes[0] / D;   // 100000
    int E = in_sizes[1];       // 1600000

    char* ws = (char*)d_ws;
    int* deg     = (int*)(ws + (size_t)(0) * (1 << 20));
    int* row_ptr = (int*)(ws + (size_t)(1) * (1 << 20));
    int* cursor  = (int*)(ws + (size_t)(2) * (1 << 20));
    int* bsums   = (int*)(ws + (size_t)(3) * (1 << 20));
    int* esrc    = (int*)(ws + (size_t)(4) * (1 << 20));   // 6.4 MB
    float* h0    = (float*)(ws + (size_t)(12) * (1 << 20)); // 19.2 MB
    float* h1    = (float*)(ws + (size_t)(32) * (1 << 20)); // 19.2 MB

    hipMemsetAsync(deg, 0, (size_t)N * sizeof(int), stream);

    int nb = (N + 1023) / 1024;
    k_hist<<<(E + 255) / 256, 256, 0, stream>>>(dst, deg, E);
    k_bsums<<<nb, 256, 0, stream>>>(deg, bsums, N);
    k_scan_small<<<1, 64, 0, stream>>>(bsums, nb);
    k_scan_write<<<nb, 256, 0, stream>>>(deg, bsums, row_ptr, cursor, N, E);
    k_fill<<<(E + 255) / 256, 256, 0, stream>>>(src, dst, cursor, esrc, E);

    int pg = (N + 15) / 16;
    k_pull<1><<<pg, 256, 0, stream>>>(feat, h0, row_ptr, esrc, N);
    k_pull<1><<<pg, 256, 0, stream>>>(h0, h1, row_ptr, esrc, N);
    k_pull<0><<<pg, 256, 0, stream>>>(h1, (float*)d_out, row_ptr, esrc, N);
}

// Round 2
// 363.745 us; speedup vs baseline: 1.2642x; 1.2642x over previous
//
#include <hip/hip_runtime.h>

#define D 48
#define BSH 6            // 64 nodes per bucket
#define BN 64
#define SUBS 8
#define CAPS 256         // per-(bucket,sub) capacity; E/(NB*8) ~ 128 expected
#define CAPT 2048        // max edges per bucket held in LDS (expected ~1024)

// ---------------- CSR build: bucketed counting sort ----------------

__global__ void k_stage(const int* __restrict__ src, const int* __restrict__ dst,
                        int* __restrict__ bcnt, int* __restrict__ stage, int E) {
    int e = blockIdx.x * 256 + threadIdx.x;
    if (e >= E) return;
    int s = src[e], d = dst[e];
    int b = d >> BSH;
    int sub = blockIdx.x & (SUBS - 1);   // ~XCD-local staging region
    int p = atomicAdd(&bcnt[b * SUBS + sub], 1);
    stage[((size_t)b * SUBS + sub) * CAPS + p] = ((d & (BN - 1)) << 17) | s;
}

// exclusive scan of per-bucket totals; single block
__global__ void k_bscan(const int* __restrict__ bcnt, int* __restrict__ bbase,
                        int* __restrict__ row_ptr, int NB, int N) {
    __shared__ int sh[256];
    __shared__ int srun;
    int t = threadIdx.x;
    if (t == 0) srun = 0;
    __syncthreads();
    int nch = (NB + 255) / 256;
    for (int c = 0; c < nch; c++) {
        int b = c * 256 + t;
        int v = 0;
        if (b < NB) {
            const int* p = bcnt + b * SUBS;
#pragma unroll
            for (int s = 0; s < SUBS; s++) v += p[s];
        }
        sh[t] = v;
        __syncthreads();
        for (int off = 1; off < 256; off <<= 1) {
            int u = (t >= off) ? sh[t - off] : 0;
            __syncthreads();
            sh[t] += u;
            __syncthreads();
        }
        int incl = sh[t];
        int run = srun;
        __syncthreads();
        if (b < NB) bbase[b] = run + incl - v;
        if (t == 255) srun = run + incl;
        __syncthreads();
    }
    if (t == 0) row_ptr[N] = srun;   // == E
}

__global__ void k_build(const int* __restrict__ stage, const int* __restrict__ bcnt,
                        const int* __restrict__ bbase, int* __restrict__ row_ptr,
                        int* __restrict__ esrc, int N) {
    int b = blockIdx.x;
    __shared__ int lbuf[CAPT];
    __shared__ int lout[CAPT];
    __shared__ int hist[BN];
    __shared__ int cur[BN];
    __shared__ int subo[SUBS + 1];
    int t = threadIdx.x;
    if (t < BN) hist[t] = 0;
    if (t == 0) {
        int acc = 0;
        for (int s = 0; s < SUBS; s++) { subo[s] = acc; acc += bcnt[b * SUBS + s]; }
        subo[SUBS] = acc;
    }
    __syncthreads();
    int cnt = subo[SUBS];
    for (int s = 0; s < SUBS; s++) {
        int o = subo[s], c = subo[s + 1] - o;
        const int* sp = stage + ((size_t)b * SUBS + s) * CAPS;
        for (int i = t; i < c; i += 256) lbuf[o + i] = sp[i];
    }
    __syncthreads();
    for (int i = t; i < cnt; i += 256) atomicAdd(&hist[lbuf[i] >> 17], 1);
    __syncthreads();
    int base = bbase[b];
    if (t < BN) {
        int orig = hist[t];
        int v = orig;
#pragma unroll
        for (int off = 1; off < BN; off <<= 1) {
            int u = __shfl_up(v, off);
            if (t >= off) v += u;
        }
        int excl = v - orig;
        cur[t] = excl;
        int node = (b << BSH) + t;
        if (node < N) row_ptr[node] = base + excl;
    }
    __syncthreads();
    for (int i = t; i < cnt; i += 256) {
        int v = lbuf[i];
        int p = atomicAdd(&cur[v >> 17], 1);
        lout[p] = v & 0x1FFFF;
    }
    __syncthreads();
    for (int i = t; i < cnt; i += 256) esrc[base + i] = lout[i];
}

// ---------------- pull-mode aggregation ----------------
// 16 lanes per node; lane l owns features l, l+16, l+32.

template <int RELU>
__global__ void k_pull(const float* __restrict__ hin, float* __restrict__ hout,
                       const int* __restrict__ row_ptr, const int* __restrict__ esrc,
                       int n) {
    int sub = threadIdx.x >> 4;
    int lane = threadIdx.x & 15;
    int node = blockIdx.x * 16 + sub;
    if (node >= n) return;
    int jb = row_ptr[node], je = row_ptr[node + 1];
    float a0 = 0.f, a1 = 0.f, a2 = 0.f;
    for (int j = jb; j < je; ++j) {
        int s = esrc[j];
        const float* r = hin + (size_t)s * D + lane;
        a0 += r[0];
        a1 += r[16];
        a2 += r[32];
    }
    if (RELU) {
        a0 = fmaxf(a0, 0.f);
        a1 = fmaxf(a1, 0.f);
        a2 = fmaxf(a2, 0.f);
    }
    float* o = hout + (size_t)node * D + lane;
    o[0] = a0;
    o[16] = a1;
    o[32] = a2;
}

extern "C" void kernel_launch(void* const* d_in, const int* in_sizes, int n_in,
                              void* d_out, int out_size, void* d_ws, size_t ws_size,
                              hipStream_t stream) {
    const float* feat = (const float*)d_in[0];
    const int* src = (const int*)d_in[1];
    const int* dst = (const int*)d_in[2];
    int N = in_sizes[0] / D;   // 100000
    int E = in_sizes[1];       // 1600000
    int NB = (N + BN - 1) >> BSH;   // 1563

    char* ws = (char*)d_ws;
    // layout (MB offsets): bcnt@0, bbase@1, row_ptr@2, esrc@3 (6.4MB),
    // h0@10 (19.2MB), stage@30 (12.8MB), h1@30 (19.2MB, aliases dead stage)
    int*   bcnt    = (int*)(ws + ((size_t)0 << 20));
    int*   bbase   = (int*)(ws + ((size_t)1 << 20));
    int*   row_ptr = (int*)(ws + ((size_t)2 << 20));
    int*   esrc    = (int*)(ws + ((size_t)3 << 20));
    float* h0      = (float*)(ws + ((size_t)10 << 20));
    int*   stage   = (int*)(ws + ((size_t)30 << 20));
    float* h1      = (float*)(ws + ((size_t)30 << 20));  // stage dead after k_build

    hipMemsetAsync(bcnt, 0, (size_t)NB * SUBS * sizeof(int), stream);

    k_stage<<<(E + 255) / 256, 256, 0, stream>>>(src, dst, bcnt, stage, E);
    k_bscan<<<1, 256, 0, stream>>>(bcnt, bbase, row_ptr, NB, N);
    k_build<<<NB, 256, 0, stream>>>(stage, bcnt, bbase, row_ptr, esrc, N);

    int pg = (N + 15) / 16;
    k_pull<1><<<pg, 256, 0, stream>>>(feat, h0, row_ptr, esrc, N);
    k_pull<1><<<pg, 256, 0, stream>>>(h0, h1, row_ptr, esrc, N);
    k_pull<0><<<pg, 256, 0, stream>>>(h1, (float*)d_out, row_ptr, esrc, N);
}

// Round 3
// 296.092 us; speedup vs baseline: 1.5530x; 1.2285x over previous
//
#include <hip/hip_runtime.h>

#define D 48
#define BSH 8            // 256 nodes per bucket
#define BN 256
#define NBMAX 400        // >= NB = 391
#define CH 256           // chunks for the counting partition
#define CAPT 5120        // max edges per bucket in LDS (expected 4092, sd 64)

// ---------------- pass A: per-chunk histogram (no global atomics) ----------------

__global__ void k_hist(const int* __restrict__ dst, int* __restrict__ histg,
                       int E, int NB, int CHE) {
    int c = blockIdx.x;
    int t = threadIdx.x;
    __shared__ int h[NBMAX];
    for (int b = t; b < NB; b += blockDim.x) h[b] = 0;
    __syncthreads();
    int lo = c * CHE, hi = min(lo + CHE, E);
    for (int i = lo + t; i < hi; i += blockDim.x)
        atomicAdd(&h[dst[i] >> BSH], 1);
    __syncthreads();
    for (int b = t; b < NB; b += blockDim.x) histg[c * NB + b] = h[b];
}

// ---------------- pass B1: per-bucket exclusive scan over chunks ----------------

__global__ void k_vscan(const int* __restrict__ histg, int* __restrict__ cbase,
                        int* __restrict__ btot, int NB) {
    int b = blockIdx.x;
    int t = threadIdx.x;   // CH threads
    __shared__ int sh[CH];
    int v = histg[t * NB + b];
    sh[t] = v;
    __syncthreads();
    for (int off = 1; off < CH; off <<= 1) {
        int u = (t >= off) ? sh[t - off] : 0;
        __syncthreads();
        sh[t] += u;
        __syncthreads();
    }
    cbase[t * NB + b] = sh[t] - v;
    if (t == CH - 1) btot[b] = sh[t];
}

// ---------------- pass B2: exclusive scan over bucket totals ----------------

__global__ void k_bscan(const int* __restrict__ btot, int* __restrict__ bbase,
                        int* __restrict__ row_ptr, int NB, int N, int E) {
    __shared__ int sh[256];
    __shared__ int srun;
    int t = threadIdx.x;
    if (t == 0) srun = 0;
    __syncthreads();
    int nch = (NB + 255) / 256;
    for (int c = 0; c < nch; c++) {
        int b = c * 256 + t;
        int v = (b < NB) ? btot[b] : 0;
        sh[t] = v;
        __syncthreads();
        for (int off = 1; off < 256; off <<= 1) {
            int u = (t >= off) ? sh[t - off] : 0;
            __syncthreads();
            sh[t] += u;
            __syncthreads();
        }
        int run = srun;
        if (b < NB) bbase[b] = run + sh[t] - v;
        __syncthreads();
        if (t == 255) srun = run + sh[255];
        __syncthreads();
    }
    if (t == 0) { bbase[NB] = E; row_ptr[N] = E; }
}

// ---------------- pass C: scatter to bucket-sorted stage (LDS cursors only) ----------------

__global__ void k_scatter(const int* __restrict__ src, const int* __restrict__ dst,
                          const int* __restrict__ bbase, const int* __restrict__ cbase,
                          int* __restrict__ stage, int E, int NB, int CHE) {
    int c = blockIdx.x;
    int t = threadIdx.x;
    __shared__ int cur[NBMAX];
    for (int b = t; b < NB; b += blockDim.x)
        cur[b] = bbase[b] + cbase[c * NB + b];
    __syncthreads();
    int lo = c * CHE, hi = min(lo + CHE, E);
    for (int i = lo + t; i < hi; i += blockDim.x) {
        int s = src[i], d = dst[i];
        int p = atomicAdd(&cur[d >> BSH], 1);
        stage[p] = ((d & (BN - 1)) << 17) | s;
    }
}

// ---------------- node-level sort within bucket (LDS) ----------------

__global__ void k_build(const int* __restrict__ stage, const int* __restrict__ bbase,
                        int* __restrict__ row_ptr, int* __restrict__ esrc,
                        int N, int NB) {
    int b = blockIdx.x;
    int t = threadIdx.x;  // 256
    __shared__ int lbuf[CAPT];
    __shared__ int lout[CAPT];
    __shared__ int hist[BN];
    __shared__ int cur[BN];
    __shared__ int sh[BN];
    int base = bbase[b];
    int cnt = min(bbase[b + 1] - base, CAPT);
    hist[t] = 0;
    __syncthreads();
    for (int i = t; i < cnt; i += 256) {
        int v = stage[base + i];
        lbuf[i] = v;
        atomicAdd(&hist[v >> 17], 1);
    }
    __syncthreads();
    int orig = hist[t];
    sh[t] = orig;
    __syncthreads();
    for (int off = 1; off < 256; off <<= 1) {
        int u = (t >= off) ? sh[t - off] : 0;
        __syncthreads();
        sh[t] += u;
        __syncthreads();
    }
    int excl = sh[t] - orig;
    cur[t] = excl;
    int node = (b << BSH) + t;
    if (node < N) row_ptr[node] = base + excl;
    __syncthreads();
    for (int i = t; i < cnt; i += 256) {
        int v = lbuf[i];
        int p = atomicAdd(&cur[v >> 17], 1);
        lout[p] = v & 0x1FFFF;
    }
    __syncthreads();
    for (int i = t; i < cnt; i += 256) esrc[base + i] = lout[i];
}

// ---------------- pull-mode aggregation ----------------
// 16 lanes per node; lane l owns features l, l+16, l+32.

template <int RELU>
__global__ void k_pull(const float* __restrict__ hin, float* __restrict__ hout,
                       const int* __restrict__ row_ptr, const int* __restrict__ esrc,
                       int n) {
    int sub = threadIdx.x >> 4;
    int lane = threadIdx.x & 15;
    int node = blockIdx.x * 16 + sub;
    if (node >= n) return;
    int jb = row_ptr[node], je = row_ptr[node + 1];
    float a0 = 0.f, a1 = 0.f, a2 = 0.f;
    for (int j = jb; j < je; ++j) {
        int s = esrc[j];
        const float* r = hin + (size_t)s * D + lane;
        a0 += r[0];
        a1 += r[16];
        a2 += r[32];
    }
    if (RELU) {
        a0 = fmaxf(a0, 0.f);
        a1 = fmaxf(a1, 0.f);
        a2 = fmaxf(a2, 0.f);
    }
    float* o = hout + (size_t)node * D + lane;
    o[0] = a0;
    o[16] = a1;
    o[32] = a2;
}

extern "C" void kernel_launch(void* const* d_in, const int* in_sizes, int n_in,
                              void* d_out, int out_size, void* d_ws, size_t ws_size,
                              hipStream_t stream) {
    const float* feat = (const float*)d_in[0];
    const int* src = (const int*)d_in[1];
    const int* dst = (const int*)d_in[2];
    int N = in_sizes[0] / D;              // 100000
    int E = in_sizes[1];                  // 1600000
    int NB = (N + BN - 1) >> BSH;         // 391
    int CHE = (E + CH - 1) / CH;          // 6250

    char* ws = (char*)d_ws;
    // layout (KB offsets): histg@0 (400K), cbase@512K (400K), btot@1024K,
    // bbase@1088K, row_ptr@2M (400K), esrc@3M (6.4M), stage@10M (6.4M),
    // h0@17M (19.2M) -> peak 36.2MB. d_out doubles as the other ping-pong buffer.
    int*   histg   = (int*)(ws + ((size_t)0 << 10));
    int*   cbase   = (int*)(ws + ((size_t)512 << 10));
    int*   btot    = (int*)(ws + ((size_t)1024 << 10));
    int*   bbase   = (int*)(ws + ((size_t)1088 << 10));
    int*   row_ptr = (int*)(ws + ((size_t)2048 << 10));
    int*   esrc    = (int*)(ws + ((size_t)3 << 20));
    int*   stage   = (int*)(ws + ((size_t)10 << 20));
    float* h0      = (float*)(ws + ((size_t)17 << 20));
    float* out     = (float*)d_out;

    k_hist<<<CH, 1024, 0, stream>>>(dst, histg, E, NB, CHE);
    k_vscan<<<NB, CH, 0, stream>>>(histg, cbase, btot, NB);
    k_bscan<<<1, 256, 0, stream>>>(btot, bbase, row_ptr, NB, N, E);
    k_scatter<<<CH, 1024, 0, stream>>>(src, dst, bbase, cbase, stage, E, NB, CHE);
    k_build<<<NB, 256, 0, stream>>>(stage, bbase, row_ptr, esrc, N, NB);

    int pg = (N + 15) / 16;
    k_pull<1><<<pg, 256, 0, stream>>>(feat, out, row_ptr, esrc, N);  // L1: feat -> out
    k_pull<1><<<pg, 256, 0, stream>>>(out, h0, row_ptr, esrc, N);    // L2: out  -> h0
    k_pull<0><<<pg, 256, 0, stream>>>(h0, out, row_ptr, esrc, N);    // L3: h0   -> out
}

// Round 4
// 221.400 us; speedup vs baseline: 2.0769x; 1.3374x over previous
//
#include <hip/hip_runtime.h>

#define D 48
#define BSH 8            // 256 nodes per bucket
#define BN 256
#define NBMAX 400        // >= NB = 391
#define CH 256           // chunks for the counting partition
#define CAPT 5120        // max edges per bucket in LDS (expected 4092, sd 64)

// ---------------- CSR build: 3-pass counting partition (unchanged from R3) ----------------

__global__ void k_hist(const int* __restrict__ dst, int* __restrict__ histg,
                       int E, int NB, int CHE) {
    int c = blockIdx.x;
    int t = threadIdx.x;
    __shared__ int h[NBMAX];
    for (int b = t; b < NB; b += blockDim.x) h[b] = 0;
    __syncthreads();
    int lo = c * CHE, hi = min(lo + CHE, E);
    for (int i = lo + t; i < hi; i += blockDim.x)
        atomicAdd(&h[dst[i] >> BSH], 1);
    __syncthreads();
    for (int b = t; b < NB; b += blockDim.x) histg[c * NB + b] = h[b];
}

__global__ void k_vscan(const int* __restrict__ histg, int* __restrict__ cbase,
                        int* __restrict__ btot, int NB) {
    int b = blockIdx.x;
    int t = threadIdx.x;   // CH threads
    __shared__ int sh[CH];
    int v = histg[t * NB + b];
    sh[t] = v;
    __syncthreads();
    for (int off = 1; off < CH; off <<= 1) {
        int u = (t >= off) ? sh[t - off] : 0;
        __syncthreads();
        sh[t] += u;
        __syncthreads();
    }
    cbase[t * NB + b] = sh[t] - v;
    if (t == CH - 1) btot[b] = sh[t];
}

__global__ void k_bscan(const int* __restrict__ btot, int* __restrict__ bbase,
                        int* __restrict__ row_ptr, int NB, int N, int E) {
    __shared__ int sh[256];
    __shared__ int srun;
    int t = threadIdx.x;
    if (t == 0) srun = 0;
    __syncthreads();
    int nch = (NB + 255) / 256;
    for (int c = 0; c < nch; c++) {
        int b = c * 256 + t;
        int v = (b < NB) ? btot[b] : 0;
        sh[t] = v;
        __syncthreads();
        for (int off = 1; off < 256; off <<= 1) {
            int u = (t >= off) ? sh[t - off] : 0;
            __syncthreads();
            sh[t] += u;
            __syncthreads();
        }
        int run = srun;
        if (b < NB) bbase[b] = run + sh[t] - v;
        __syncthreads();
        if (t == 255) srun = run + sh[255];
        __syncthreads();
    }
    if (t == 0) { bbase[NB] = E; row_ptr[N] = E; }
}

__global__ void k_scatter(const int* __restrict__ src, const int* __restrict__ dst,
                          const int* __restrict__ bbase, const int* __restrict__ cbase,
                          int* __restrict__ stage, int E, int NB, int CHE) {
    int c = blockIdx.x;
    int t = threadIdx.x;
    __shared__ int cur[NBMAX];
    for (int b = t; b < NB; b += blockDim.x)
        cur[b] = bbase[b] + cbase[c * NB + b];
    __syncthreads();
    int lo = c * CHE, hi = min(lo + CHE, E);
    for (int i = lo + t; i < hi; i += blockDim.x) {
        int s = src[i], d = dst[i];
        int p = atomicAdd(&cur[d >> BSH], 1);
        stage[p] = ((d & (BN - 1)) << 17) | s;
    }
}

__global__ void k_build(const int* __restrict__ stage, const int* __restrict__ bbase,
                        int* __restrict__ row_ptr, int* __restrict__ esrc,
                        int N, int NB) {
    int b = blockIdx.x;
    int t = threadIdx.x;  // 256
    __shared__ int lbuf[CAPT];
    __shared__ int lout[CAPT];
    __shared__ int hist[BN];
    __shared__ int cur[BN];
    __shared__ int sh[BN];
    int base = bbase[b];
    int cnt = min(bbase[b + 1] - base, CAPT);
    hist[t] = 0;
    __syncthreads();
    for (int i = t; i < cnt; i += 256) {
        int v = stage[base + i];
        lbuf[i] = v;
        atomicAdd(&hist[v >> 17], 1);
    }
    __syncthreads();
    int orig = hist[t];
    sh[t] = orig;
    __syncthreads();
    for (int off = 1; off < 256; off <<= 1) {
        int u = (t >= off) ? sh[t - off] : 0;
        __syncthreads();
        sh[t] += u;
        __syncthreads();
    }
    int excl = sh[t] - orig;
    cur[t] = excl;
    int node = (b << BSH) + t;
    if (node < N) row_ptr[node] = base + excl;
    __syncthreads();
    for (int i = t; i < cnt; i += 256) {
        int v = lbuf[i];
        int p = atomicAdd(&cur[v >> 17], 1);
        lout[p] = v & 0x1FFFF;
    }
    __syncthreads();
    for (int i = t; i < cnt; i += 256) esrc[base + i] = lout[i];
}

// ---------------- bf16 helpers ----------------

static __device__ inline unsigned int f2bf_rne(float x) {
    unsigned int u = __float_as_uint(x);
    return (u + 0x7FFFu + ((u >> 16) & 1u)) >> 16;
}
static __device__ inline unsigned int pack2(float lo, float hi) {
    return f2bf_rne(lo) | (f2bf_rne(hi) << 16);
}
static __device__ inline float bf_lo(unsigned int u) { return __uint_as_float(u << 16); }
static __device__ inline float bf_hi(unsigned int u) { return __uint_as_float(u & 0xFFFF0000u); }

// features f32 -> packed bf16 (row-major, 24 uints per node row)
__global__ void k_cvt(const float* __restrict__ in, unsigned int* __restrict__ out, int n4) {
    int i = blockIdx.x * 256 + threadIdx.x;   // one float4 -> uint2
    if (i >= n4) return;
    float4 v = ((const float4*)in)[i];
    ((uint2*)out)[i] = make_uint2(pack2(v.x, v.y), pack2(v.z, v.w));
}

// ---------------- pull-mode aggregation, bf16 rows ----------------
// 8 lanes per node; lane l owns uints {2l,2l+1} (feats 4l..4l+3) and uint {16+l}
// (feats 32+2l, 33+2l). Loads per edge per lane: uint2 + uint = 12B; 96B/row.

template <int RELU, int OUTF32>
__global__ void k_pull(const unsigned int* __restrict__ hin, void* __restrict__ hout,
                       const int* __restrict__ row_ptr, const int* __restrict__ esrc,
                       int n) {
    int grp = threadIdx.x >> 3;
    int lane = threadIdx.x & 7;
    int node = blockIdx.x * 32 + grp;
    if (node >= n) return;
    int jb = row_ptr[node], je = row_ptr[node + 1];
    float a0 = 0.f, a1 = 0.f, a2 = 0.f, a3 = 0.f, a4 = 0.f, a5 = 0.f;
    int j = jb;
    for (; j + 1 < je; j += 2) {
        int s0 = esrc[j], s1 = esrc[j + 1];
        const unsigned int* r0 = hin + s0 * 24;
        const unsigned int* r1 = hin + s1 * 24;
        uint2 q0 = *(const uint2*)(r0 + 2 * lane);
        unsigned int w0 = r0[16 + lane];
        uint2 q1 = *(const uint2*)(r1 + 2 * lane);
        unsigned int w1 = r1[16 + lane];
        a0 += bf_lo(q0.x); a1 += bf_hi(q0.x);
        a2 += bf_lo(q0.y); a3 += bf_hi(q0.y);
        a4 += bf_lo(w0);   a5 += bf_hi(w0);
        a0 += bf_lo(q1.x); a1 += bf_hi(q1.x);
        a2 += bf_lo(q1.y); a3 += bf_hi(q1.y);
        a4 += bf_lo(w1);   a5 += bf_hi(w1);
    }
    if (j < je) {
        int s0 = esrc[j];
        const unsigned int* r0 = hin + s0 * 24;
        uint2 q0 = *(const uint2*)(r0 + 2 * lane);
        unsigned int w0 = r0[16 + lane];
        a0 += bf_lo(q0.x); a1 += bf_hi(q0.x);
        a2 += bf_lo(q0.y); a3 += bf_hi(q0.y);
        a4 += bf_lo(w0);   a5 += bf_hi(w0);
    }
    if (RELU) {
        a0 = fmaxf(a0, 0.f); a1 = fmaxf(a1, 0.f); a2 = fmaxf(a2, 0.f);
        a3 = fmaxf(a3, 0.f); a4 = fmaxf(a4, 0.f); a5 = fmaxf(a5, 0.f);
    }
    if (OUTF32) {
        float* o = (float*)hout + (size_t)node * D;
        *(float4*)(o + 4 * lane) = make_float4(a0, a1, a2, a3);
        *(float2*)(o + 32 + 2 * lane) = make_float2(a4, a5);
    } else {
        unsigned int* o = (unsigned int*)hout + node * 24;
        *(uint2*)(o + 2 * lane) = make_uint2(pack2(a0, a1), pack2(a2, a3));
        o[16 + lane] = pack2(a4, a5);
    }
}

extern "C" void kernel_launch(void* const* d_in, const int* in_sizes, int n_in,
                              void* d_out, int out_size, void* d_ws, size_t ws_size,
                              hipStream_t stream) {
    const float* feat = (const float*)d_in[0];
    const int* src = (const int*)d_in[1];
    const int* dst = (const int*)d_in[2];
    int N = in_sizes[0] / D;              // 100000
    int E = in_sizes[1];                  // 1600000
    int NB = (N + BN - 1) >> BSH;         // 391
    int CHE = (E + CH - 1) / CH;          // 6250

    char* ws = (char*)d_ws;
    // layout: histg@0(400K), cbase@512K(400K), btot@1024K, bbase@1088K,
    // row_ptr@2M(400K), esrc@3M(6.4M), stage@10M(6.4M),
    // featb@17M(9.6M), hb0@27M(9.6M) -> peak 36.6MB
    int*   histg   = (int*)(ws + ((size_t)0 << 10));
    int*   cbase   = (int*)(ws + ((size_t)512 << 10));
    int*   btot    = (int*)(ws + ((size_t)1024 << 10));
    int*   bbase   = (int*)(ws + ((size_t)1088 << 10));
    int*   row_ptr = (int*)(ws + ((size_t)2048 << 10));
    int*   esrc    = (int*)(ws + ((size_t)3 << 20));
    int*   stage   = (int*)(ws + ((size_t)10 << 20));
    unsigned int* featb = (unsigned int*)(ws + ((size_t)17 << 20));
    unsigned int* hb0   = (unsigned int*)(ws + ((size_t)27 << 20));

    k_hist<<<CH, 1024, 0, stream>>>(dst, histg, E, NB, CHE);
    k_vscan<<<NB, CH, 0, stream>>>(histg, cbase, btot, NB);
    k_bscan<<<1, 256, 0, stream>>>(btot, bbase, row_ptr, NB, N, E);
    k_scatter<<<CH, 1024, 0, stream>>>(src, dst, bbase, cbase, stage, E, NB, CHE);
    k_build<<<NB, 256, 0, stream>>>(stage, bbase, row_ptr, esrc, N, NB);

    int n4 = N * D / 4;
    k_cvt<<<(n4 + 255) / 256, 256, 0, stream>>>(feat, featb, n4);

    int pg = (N + 31) / 32;
    k_pull<1, 0><<<pg, 256, 0, stream>>>(featb, hb0, row_ptr, esrc, N);   // L1: featb -> hb0
    k_pull<1, 0><<<pg, 256, 0, stream>>>(hb0, featb, row_ptr, esrc, N);   // L2: hb0 -> featb
    k_pull<0, 1><<<pg, 256, 0, stream>>>(featb, d_out, row_ptr, esrc, N); // L3: featb -> d_out (f32)
}

// Round 5
// 213.511 us; speedup vs baseline: 2.1537x; 1.0369x over previous
//
#include <hip/hip_runtime.h>

#define D 48
#define BSH 8            // 256 nodes per bucket
#define BN 256
#define NBMAX 400        // >= NB = 391
#define CH 256           // chunks for the counting partition
#define CAPT 5120        // max edges per bucket in LDS (expected 4092, sd 64)

// ---------------- CSR build: 3-pass counting partition ----------------

__global__ void k_hist(const int* __restrict__ dst, int* __restrict__ histg,
                       int E, int NB, int CHE) {
    int c = blockIdx.x;
    int t = threadIdx.x;
    __shared__ int h[NBMAX];
    for (int b = t; b < NB; b += blockDim.x) h[b] = 0;
    __syncthreads();
    int lo = c * CHE, hi = min(lo + CHE, E);
    for (int i = lo + t; i < hi; i += blockDim.x)
        atomicAdd(&h[dst[i] >> BSH], 1);
    __syncthreads();
    for (int b = t; b < NB; b += blockDim.x) histg[c * NB + b] = h[b];
}

__global__ void k_vscan(const int* __restrict__ histg, int* __restrict__ cbase,
                        int* __restrict__ btot, int NB) {
    int b = blockIdx.x;
    int t = threadIdx.x;   // CH threads
    __shared__ int sh[CH];
    int v = histg[t * NB + b];
    sh[t] = v;
    __syncthreads();
    for (int off = 1; off < CH; off <<= 1) {
        int u = (t >= off) ? sh[t - off] : 0;
        __syncthreads();
        sh[t] += u;
        __syncthreads();
    }
    cbase[t * NB + b] = sh[t] - v;
    if (t == CH - 1) btot[b] = sh[t];
}

__global__ void k_bscan(const int* __restrict__ btot, int* __restrict__ bbase,
                        int* __restrict__ row_ptr, int NB, int N, int E) {
    __shared__ int sh[256];
    __shared__ int srun;
    int t = threadIdx.x;
    if (t == 0) srun = 0;
    __syncthreads();
    int nch = (NB + 255) / 256;
    for (int c = 0; c < nch; c++) {
        int b = c * 256 + t;
        int v = (b < NB) ? btot[b] : 0;
        sh[t] = v;
        __syncthreads();
        for (int off = 1; off < 256; off <<= 1) {
            int u = (t >= off) ? sh[t - off] : 0;
            __syncthreads();
            sh[t] += u;
            __syncthreads();
        }
        int run = srun;
        if (b < NB) bbase[b] = run + sh[t] - v;
        __syncthreads();
        if (t == 255) srun = run + sh[255];
        __syncthreads();
    }
    if (t == 0) { bbase[NB] = E; row_ptr[N] = E; }
}

__global__ void k_scatter(const int* __restrict__ src, const int* __restrict__ dst,
                          const int* __restrict__ bbase, const int* __restrict__ cbase,
                          int* __restrict__ stage, int E, int NB, int CHE) {
    int c = blockIdx.x;
    int t = threadIdx.x;
    __shared__ int cur[NBMAX];
    for (int b = t; b < NB; b += blockDim.x)
        cur[b] = bbase[b] + cbase[c * NB + b];
    __syncthreads();
    int lo = c * CHE, hi = min(lo + CHE, E);
    for (int i = lo + t; i < hi; i += blockDim.x) {
        int s = src[i], d = dst[i];
        int p = atomicAdd(&cur[d >> BSH], 1);
        stage[p] = ((d & (BN - 1)) << 17) | s;
    }
}

__global__ void k_build(const int* __restrict__ stage, const int* __restrict__ bbase,
                        int* __restrict__ row_ptr, int* __restrict__ esrc,
                        int N, int NB) {
    int b = blockIdx.x;
    int t = threadIdx.x;  // 256
    __shared__ int lbuf[CAPT];
    __shared__ int lout[CAPT];
    __shared__ int hist[BN];
    __shared__ int cur[BN];
    __shared__ int sh[BN];
    int base = bbase[b];
    int cnt = min(bbase[b + 1] - base, CAPT);
    hist[t] = 0;
    __syncthreads();
    for (int i = t; i < cnt; i += 256) {
        int v = stage[base + i];
        lbuf[i] = v;
        atomicAdd(&hist[v >> 17], 1);
    }
    __syncthreads();
    int orig = hist[t];
    sh[t] = orig;
    __syncthreads();
    for (int off = 1; off < 256; off <<= 1) {
        int u = (t >= off) ? sh[t - off] : 0;
        __syncthreads();
        sh[t] += u;
        __syncthreads();
    }
    int excl = sh[t] - orig;
    cur[t] = excl;
    int node = (b << BSH) + t;
    if (node < N) row_ptr[node] = base + excl;
    __syncthreads();
    for (int i = t; i < cnt; i += 256) {
        int v = lbuf[i];
        int p = atomicAdd(&cur[v >> 17], 1);
        lout[p] = v & 0x1FFFF;
    }
    __syncthreads();
    for (int i = t; i < cnt; i += 256) esrc[base + i] = lout[i];
}

// ---------------- bf16 helpers ----------------

static __device__ inline unsigned int f2bf_rne(float x) {
    unsigned int u = __float_as_uint(x);
    return (u + 0x7FFFu + ((u >> 16) & 1u)) >> 16;
}
static __device__ inline unsigned int pack2(float lo, float hi) {
    return f2bf_rne(lo) | (f2bf_rne(hi) << 16);
}
static __device__ inline float bf_lo(unsigned int u) { return __uint_as_float(u << 16); }
static __device__ inline float bf_hi(unsigned int u) { return __uint_as_float(u & 0xFFFF0000u); }

// features f32 -> packed bf16 (row-major, 24 uints per node row)
__global__ void k_cvt(const float* __restrict__ in, unsigned int* __restrict__ out, int n4) {
    int i = blockIdx.x * 256 + threadIdx.x;   // one float4 -> uint2
    if (i >= n4) return;
    float4 v = ((const float4*)in)[i];
    ((uint2*)out)[i] = make_uint2(pack2(v.x, v.y), pack2(v.z, v.w));
}

// ---------------- pull-mode aggregation, bf16 rows ----------------
// 8 lanes per node; lane l owns uints {2l,2l+1} (feats 4l..4l+3) and uint {16+l}
// (feats 32+2l, 33+2l). 12B/lane/edge; 96B/row. Unroll 8: up to 16 feature
// loads + 8 esrc loads in flight per wave-group -> latency hiding.

template <int RELU, int OUTF32>
__global__ void k_pull(const unsigned int* __restrict__ hin, void* __restrict__ hout,
                       const int* __restrict__ row_ptr, const int* __restrict__ esrc,
                       int n) {
    int grp = threadIdx.x >> 3;
    int lane = threadIdx.x & 7;
    int node = blockIdx.x * 32 + grp;
    if (node >= n) return;
    int jb = row_ptr[node], je = row_ptr[node + 1];
    float a0 = 0.f, a1 = 0.f, a2 = 0.f, a3 = 0.f, a4 = 0.f, a5 = 0.f;
    int j = jb;
    int je8 = jb + ((je - jb) & ~7);
    for (; j < je8; j += 8) {
        int s[8];
#pragma unroll
        for (int u = 0; u < 8; u++) s[u] = esrc[j + u];
        uint2 q[8];
        unsigned int w[8];
#pragma unroll
        for (int u = 0; u < 8; u++) {
            const unsigned int* r = hin + s[u] * 24;
            q[u] = *(const uint2*)(r + 2 * lane);
            w[u] = r[16 + lane];
        }
#pragma unroll
        for (int u = 0; u < 8; u++) {
            a0 += bf_lo(q[u].x); a1 += bf_hi(q[u].x);
            a2 += bf_lo(q[u].y); a3 += bf_hi(q[u].y);
            a4 += bf_lo(w[u]);   a5 += bf_hi(w[u]);
        }
    }
    if (j < je) {
        int rem = je - j;   // 1..7
        int s[7];
#pragma unroll
        for (int u = 0; u < 7; u++) s[u] = (u < rem) ? esrc[j + u] : s[0];
        // guard: if rem>=1, s[0] valid; duplicates masked below
        uint2 q[7];
        unsigned int w[7];
#pragma unroll
        for (int u = 0; u < 7; u++) {
            const unsigned int* r = hin + s[u] * 24;
            if (u < rem) {
                q[u] = *(const uint2*)(r + 2 * lane);
                w[u] = r[16 + lane];
            }
        }
#pragma unroll
        for (int u = 0; u < 7; u++) {
            if (u < rem) {
                a0 += bf_lo(q[u].x); a1 += bf_hi(q[u].x);
                a2 += bf_lo(q[u].y); a3 += bf_hi(q[u].y);
                a4 += bf_lo(w[u]);   a5 += bf_hi(w[u]);
            }
        }
    }
    if (RELU) {
        a0 = fmaxf(a0, 0.f); a1 = fmaxf(a1, 0.f); a2 = fmaxf(a2, 0.f);
        a3 = fmaxf(a3, 0.f); a4 = fmaxf(a4, 0.f); a5 = fmaxf(a5, 0.f);
    }
    if (OUTF32) {
        float* o = (float*)hout + (size_t)node * D;
        *(float4*)(o + 4 * lane) = make_float4(a0, a1, a2, a3);
        *(float2*)(o + 32 + 2 * lane) = make_float2(a4, a5);
    } else {
        unsigned int* o = (unsigned int*)hout + node * 24;
        *(uint2*)(o + 2 * lane) = make_uint2(pack2(a0, a1), pack2(a2, a3));
        o[16 + lane] = pack2(a4, a5);
    }
}

extern "C" void kernel_launch(void* const* d_in, const int* in_sizes, int n_in,
                              void* d_out, int out_size, void* d_ws, size_t ws_size,
                              hipStream_t stream) {
    const float* feat = (const float*)d_in[0];
    const int* src = (const int*)d_in[1];
    const int* dst = (const int*)d_in[2];
    int N = in_sizes[0] / D;              // 100000
    int E = in_sizes[1];                  // 1600000
    int NB = (N + BN - 1) >> BSH;         // 391
    int CHE = (E + CH - 1) / CH;          // 6250

    char* ws = (char*)d_ws;
    // layout: histg@0(400K), cbase@512K(400K), btot@1024K, bbase@1088K,
    // row_ptr@2M(400K), esrc@3M(6.4M), stage@10M(6.4M),
    // featb@17M(9.6M), hb0@27M(9.6M) -> peak 36.6MB
    int*   histg   = (int*)(ws + ((size_t)0 << 10));
    int*   cbase   = (int*)(ws + ((size_t)512 << 10));
    int*   btot    = (int*)(ws + ((size_t)1024 << 10));
    int*   bbase   = (int*)(ws + ((size_t)1088 << 10));
    int*   row_ptr = (int*)(ws + ((size_t)2048 << 10));
    int*   esrc    = (int*)(ws + ((size_t)3 << 20));
    int*   stage   = (int*)(ws + ((size_t)10 << 20));
    unsigned int* featb = (unsigned int*)(ws + ((size_t)17 << 20));
    unsigned int* hb0   = (unsigned int*)(ws + ((size_t)27 << 20));

    k_hist<<<CH, 1024, 0, stream>>>(dst, histg, E, NB, CHE);
    k_vscan<<<NB, CH, 0, stream>>>(histg, cbase, btot, NB);
    k_bscan<<<1, 256, 0, stream>>>(btot, bbase, row_ptr, NB, N, E);
    k_scatter<<<CH, 1024, 0, stream>>>(src, dst, bbase, cbase, stage, E, NB, CHE);
    k_build<<<NB, 256, 0, stream>>>(stage, bbase, row_ptr, esrc, N, NB);

    int n4 = N * D / 4;
    k_cvt<<<(n4 + 255) / 256, 256, 0, stream>>>(feat, featb, n4);

    int pg = (N + 31) / 32;
    k_pull<1, 0><<<pg, 256, 0, stream>>>(featb, hb0, row_ptr, esrc, N);   // L1: featb -> hb0
    k_pull<1, 0><<<pg, 256, 0, stream>>>(hb0, featb, row_ptr, esrc, N);   // L2: hb0 -> featb
    k_pull<0, 1><<<pg, 256, 0, stream>>>(featb, d_out, row_ptr, esrc, N); // L3: featb -> d_out (f32)
}